// Round 1
// baseline (104.037 us; speedup 1.0000x reference)
//
#include <hip/hip_runtime.h>

// ODE func: out = tanh(y @ W1^T + b1) @ W2^T + b2
// y: [B,2] f32, W1: [50,2], b1: [50], W2: [2,50], b2: [2], out: [B,2] f32
// B = 2,000,000 (divisible by 4 -> each thread owns 4 full rows, no partial rows)

#define NROWS 2000000
#define HID 50
#define ROWS_PER_THREAD 4

__global__ __launch_bounds__(256) void odefunc_kernel(
    const float* __restrict__ y,
    const float* __restrict__ W1,   // [HID][2] row-major
    const float* __restrict__ b1,   // [HID]
    const float* __restrict__ W2,   // [2][HID] row-major
    const float* __restrict__ b2,   // [2]
    float* __restrict__ out)        // [B][2]
{
    const int tid = blockIdx.x * blockDim.x + threadIdx.x;
    const long long row0 = (long long)tid * ROWS_PER_THREAD;
    if (row0 >= NROWS) return;

    // Load 4 rows = 8 floats as two float4 (coalesced, 16B/lane)
    const float4 a = *reinterpret_cast<const float4*>(y + row0 * 2);
    const float4 b = *reinterpret_cast<const float4*>(y + row0 * 2 + 4);

    float y0[ROWS_PER_THREAD], y1[ROWS_PER_THREAD];
    y0[0] = a.x; y1[0] = a.y;
    y0[1] = a.z; y1[1] = a.w;
    y0[2] = b.x; y1[2] = b.y;
    y0[3] = b.z; y1[3] = b.w;

    const float bias0 = b2[0];
    const float bias1 = b2[1];

    float o0[ROWS_PER_THREAD], o1[ROWS_PER_THREAD];
#pragma unroll
    for (int r = 0; r < ROWS_PER_THREAD; ++r) { o0[r] = bias0; o1[r] = bias1; }

    // 2*log2(e): tanh(z) = 1 - 2/(exp2(z*2*log2e) + 1)
    const float TWO_LOG2E = 2.8853900817779268f;

#pragma unroll
    for (int j = 0; j < HID; ++j) {
        const float w0 = W1[2 * j];
        const float w1 = W1[2 * j + 1];
        const float bb = b1[j];
        const float v0 = W2[j];
        const float v1 = W2[HID + j];
#pragma unroll
        for (int r = 0; r < ROWS_PER_THREAD; ++r) {
            float z = fmaf(w0, y0[r], fmaf(w1, y1[r], bb));
            float e = __builtin_amdgcn_exp2f(z * TWO_LOG2E);   // v_exp_f32
            float h = fmaf(-2.0f, __builtin_amdgcn_rcpf(e + 1.0f), 1.0f); // v_rcp_f32
            o0[r] = fmaf(v0, h, o0[r]);
            o1[r] = fmaf(v1, h, o1[r]);
        }
    }

    // Store 4 rows = 8 floats as two float4
    float4 s0, s1;
    s0.x = o0[0]; s0.y = o1[0]; s0.z = o0[1]; s0.w = o1[1];
    s1.x = o0[2]; s1.y = o1[2]; s1.z = o0[3]; s1.w = o1[3];
    *reinterpret_cast<float4*>(out + row0 * 2) = s0;
    *reinterpret_cast<float4*>(out + row0 * 2 + 4) = s1;
}

extern "C" void kernel_launch(void* const* d_in, const int* in_sizes, int n_in,
                              void* d_out, int out_size, void* d_ws, size_t ws_size,
                              hipStream_t stream) {
    // setup_inputs order: t, y, W1, b1, W2, b2
    const float* y  = (const float*)d_in[1];
    const float* W1 = (const float*)d_in[2];
    const float* b1 = (const float*)d_in[3];
    const float* W2 = (const float*)d_in[4];
    const float* b2 = (const float*)d_in[5];
    float* out = (float*)d_out;

    const int threads_needed = NROWS / ROWS_PER_THREAD;     // 500,000
    const int block = 256;
    const int grid = (threads_needed + block - 1) / block;  // 1954

    odefunc_kernel<<<grid, block, 0, stream>>>(y, W1, b1, W2, b2, out);
}